// Round 4
// baseline (329.452 us; speedup 1.0000x reference)
//
#include <hip/hip_runtime.h>
#include <hip/hip_fp16.h>

#define CH   16
#define HID  32
#define HIN  254
#define WIN  254
#define HO   128
#define WO   128
#define NB   64
#define SLEN (HO * WO)          // 16384
#define CHUNK 16
#define WARM  16
#define NCHUNK (SLEN / CHUNK)   // 1024

typedef _Float16 v8h __attribute__((ext_vector_type(8)));
typedef float    v4f __attribute__((ext_vector_type(4)));
typedef float    v2f __attribute__((ext_vector_type(2)));
typedef unsigned int v4u __attribute__((ext_vector_type(4)));

__device__ __forceinline__ float fast_tanh(float x) {
    float ax = __builtin_fabsf(x);
    float e = exp2f(ax * -2.8853900817779268f);
    float r = (1.0f - e) * __builtin_amdgcn_rcpf(1.0f + e);
    return __builtin_copysignf(r, x);
}

// ---------------- K1: pad + L2 pool -> pooled f16 in (N, S, C) -----------
// thread = (n, y, x-pair). 3-tap window: out xc <- input cols 2xc-2,2xc-1,2xc.
// Pair (2px, 2px+1): s0 = x[4px-2]^2+x[4px-1]^2+x[4px]^2
//                    s1 = x[4px]^2 +x[4px+1]^2+x[4px+2]^2
// Channels processed in groups of 4 with all 36 v2f loads issued up-front (ILP).
__global__ __launch_bounds__(256) void k_pool(const float* __restrict__ x,
                                              _Float16* __restrict__ pooled) {
    const int tid = threadIdx.x;
    const int px  = tid & 63;          // x-pair: outputs 2*px, 2*px+1
    const int wy  = tid >> 6;
    const int y   = blockIdx.x * 4 + wy;
    const int n   = blockIdx.y;

    int r[3];
#pragma unroll
    for (int k = 0; k < 3; ++k) r[k] = min(max(2 * y - 2 + k, 0), HIN - 1);

    const bool left  = (px == 0);
    const bool right = (px == 63);
    const int c0 = left  ? 0   : 4 * px - 2;   // cols (4px-2, 4px-1)
    const int c1 = 4 * px;                      // cols (4px, 4px+1)
    const int c2 = right ? 252 : 4 * px + 2;   // cols (4px+2, 4px+3)

    const float* xn = x + (size_t)n * CH * HIN * WIN;
    _Float16 ph[2][CH];

#pragma unroll
    for (int cg = 0; cg < 4; ++cg) {
        v2f L[4][3][3];
#pragma unroll
        for (int cc = 0; cc < 4; ++cc) {
            const float* bc = xn + (size_t)(cg * 4 + cc) * HIN * WIN;
#pragma unroll
            for (int k = 0; k < 3; ++k) {
                const float* rp = bc + (size_t)r[k] * WIN;
                L[cc][k][0] = *(const v2f*)(rp + c0);
                L[cc][k][1] = *(const v2f*)(rp + c1);
                L[cc][k][2] = *(const v2f*)(rp + c2);
            }
        }
#pragma unroll
        for (int cc = 0; cc < 4; ++cc) {
            float s0 = 0.f, s1 = 0.f;
#pragma unroll
            for (int k = 0; k < 3; ++k) {
                v2f L0 = L[cc][k][0], L1 = L[cc][k][1], L2 = L[cc][k][2];
                if (left)  L0[1] = L0[0];   // cols(-2,-1)->x0 (L0[0] already x0)
                if (right) L2[0] = L2[1];   // col 254 -> x253
                s0 += L0[0] * L0[0] + L0[1] * L0[1] + L1[0] * L1[0];
                s1 += L1[0] * L1[0] + L1[1] * L1[1] + L2[0] * L2[0];
            }
            ph[0][cg * 4 + cc] = (_Float16)sqrtf(s0);
            ph[1][cg * 4 + cc] = (_Float16)sqrtf(s1);
        }
    }

    const size_t t = (size_t)y * WO + 2 * px;
    v4u* dst = (v4u*)(pooled + ((size_t)n * SLEN + t) * CH);
    dst[0] = *(const v4u*)&ph[0][0];
    dst[1] = *(const v4u*)&ph[0][8];
    dst[2] = *(const v4u*)&ph[1][0];
    dst[3] = *(const v4u*)&ph[1][8];
}

// ---------------- K2: fused xproj + Elman RNN + out-proj + residual ------
// 1 wave = all 64 batches. Layouts (v_mfma_f32_16x16x32_f16, g=l>>4, q=l&15):
//   A[m][k]: m=q, k=8g+e ;  B[k][n]: n=q, k=8g+e ;  D[m][n]: n=q, m=4g+r
// LDS row b: [ h(32 halfs) | p(16 halfs) | zero-pad(16) | pad to 72 ]
__global__ __launch_bounds__(64) void k_rnn(const _Float16* __restrict__ pooled,
                                            const float* __restrict__ Wih,
                                            const float* __restrict__ Whh,
                                            const float* __restrict__ bih,
                                            const float* __restrict__ bhh,
                                            const float* __restrict__ Wfc,
                                            const float* __restrict__ bfc,
                                            float* __restrict__ out) {
    const int l = threadIdx.x;
    const int g = l >> 4;
    const int q = l & 15;
    const int cid = blockIdx.x;
    const int start  = cid * CHUNK;
    const int warm   = min(WARM, start);
    const int t0     = start - warm;
    const int nsteps = warm + CHUNK;           // 16 or 32, even

    __shared__ _Float16 hbuf[64][72];          // 144B rows (bank-spread)
    {   // zero the pf K-pad region (cols 48..63) once
        v4u z = {0u, 0u, 0u, 0u};
        *(v4u*)&hbuf[l][48] = z;
        *(v4u*)&hbuf[l][56] = z;
    }

    // B fragments (constant): Whh (32x32), Wih (32x16, K-padded), Wfc (16x32)
    v8h bWhh[2], bWih[2], bWfc;
#pragma unroll
    for (int nt = 0; nt < 2; ++nt) {
        const float* wr = Whh + (size_t)(nt * 16 + q) * HID + 8 * g;
#pragma unroll
        for (int e = 0; e < 8; ++e) bWhh[nt][e] = (_Float16)wr[e];
        const float* wi = Wih + (size_t)(nt * 16 + q) * CH;
#pragma unroll
        for (int e = 0; e < 8; ++e)
            bWih[nt][e] = (g < 2) ? (_Float16)wi[8 * g + e] : (_Float16)0.f;
    }
#pragma unroll
    for (int e = 0; e < 8; ++e) bWfc[e] = (_Float16)Wfc[(size_t)q * HID + 8 * g + e];

    float biasH[2];
#pragma unroll
    for (int nt = 0; nt < 2; ++nt) biasH[nt] = bih[nt * 16 + q] + bhh[nt * 16 + q];
    const float biasC = bfc[q];

    v8h af[4];                                  // h state, A-fragments
#pragma unroll
    for (int mt = 0; mt < 4; ++mt)
#pragma unroll
        for (int e = 0; e < 8; ++e) af[mt][e] = (_Float16)0.f;

    const v4u* __restrict__ ppl = (const v4u*)(pooled + (size_t)l * SLEN * CH);
    v4u pA[2], pB[2];
    pA[0] = ppl[(size_t)t0 * 2];       pA[1] = ppl[(size_t)t0 * 2 + 1];
    pB[0] = ppl[(size_t)(t0 + 1) * 2]; pB[1] = ppl[(size_t)(t0 + 1) * 2 + 1];

#define RNN_STEP(PB, TT, EMIT)                                                 \
    {                                                                          \
        const int t = (TT);                                                    \
        /* stage p(t) into LDS cols 32..47, then prefetch p(t+2) */            \
        *(v4u*)&hbuf[l][32] = PB[0];                                           \
        *(v4u*)&hbuf[l][40] = PB[1];                                           \
        {                                                                      \
            int tn = t + 2; if (tn > SLEN - 1) tn = SLEN - 1;                  \
            PB[0] = ppl[(size_t)tn * 2];                                       \
            PB[1] = ppl[(size_t)tn * 2 + 1];                                   \
        }                                                                      \
        v8h pf[4];                                                             \
        _Pragma("unroll")                                                      \
        for (int mt = 0; mt < 4; ++mt)                                         \
            pf[mt] = *(const v8h*)&hbuf[mt * 16 + q][32 + 8 * g];              \
        v4f acc[4][2];                                                         \
        _Pragma("unroll")                                                      \
        for (int mt = 0; mt < 4; ++mt)                                         \
            _Pragma("unroll")                                                  \
            for (int nt = 0; nt < 2; ++nt) {                                   \
                v4f ai = {biasH[nt], biasH[nt], biasH[nt], biasH[nt]};         \
                ai = __builtin_amdgcn_mfma_f32_16x16x32_f16(pf[mt], bWih[nt],  \
                                                            ai, 0, 0, 0);      \
                acc[mt][nt] = __builtin_amdgcn_mfma_f32_16x16x32_f16(          \
                    af[mt], bWhh[nt], ai, 0, 0, 0);                            \
            }                                                                  \
        _Pragma("unroll")                                                      \
        for (int mt = 0; mt < 4; ++mt)                                         \
            _Pragma("unroll")                                                  \
            for (int nt = 0; nt < 2; ++nt)                                     \
                _Pragma("unroll")                                              \
                for (int r = 0; r < 4; ++r)                                    \
                    hbuf[mt * 16 + 4 * g + r][nt * 16 + q] =                   \
                        (_Float16)fast_tanh(acc[mt][nt][r]);                   \
        _Pragma("unroll")                                                      \
        for (int mt = 0; mt < 4; ++mt)                                         \
            af[mt] = *(const v8h*)&hbuf[mt * 16 + q][8 * g];                   \
        if (EMIT) {                                                            \
            _Pragma("unroll")                                                  \
            for (int mt = 0; mt < 4; ++mt) {                                   \
                v4f pj = {biasC, biasC, biasC, biasC};                         \
                pj = __builtin_amdgcn_mfma_f32_16x16x32_f16(af[mt], bWfc, pj,  \
                                                            0, 0, 0);          \
                _Pragma("unroll")                                              \
                for (int r = 0; r < 4; ++r) {                                  \
                    const int b = mt * 16 + 4 * g + r;                         \
                    out[(size_t)(b * CH + q) * SLEN + t] =                     \
                        pj[r] + (float)hbuf[b][32 + q];                        \
                }                                                              \
            }                                                                  \
        }                                                                      \
    }

    for (int st = 0; st < nsteps; st += 2) {
        RNN_STEP(pA, t0 + st,     (t0 + st)     >= start)
        RNN_STEP(pB, t0 + st + 1, (t0 + st + 1) >= start)
    }
#undef RNN_STEP
}

__global__ void k_sentinel(float* o) { o[threadIdx.x] = -12345.0f; }

extern "C" void kernel_launch(void* const* d_in, const int* in_sizes, int n_in,
                              void* d_out, int out_size, void* d_ws, size_t ws_size,
                              hipStream_t stream) {
    const float* x   = (const float*)d_in[0];
    const float* Wih = (const float*)d_in[1];
    const float* Whh = (const float*)d_in[2];
    const float* bih = (const float*)d_in[3];
    const float* bhh = (const float*)d_in[4];
    const float* Wfc = (const float*)d_in[5];
    const float* bfc = (const float*)d_in[6];
    float* out = (float*)d_out;

    const size_t poolB = (size_t)NB * SLEN * CH * sizeof(_Float16);  // 32 MiB
    if (ws_size < poolB) {
        k_sentinel<<<1, 64, 0, stream>>>(out);
        return;
    }
    _Float16* pooled = (_Float16*)d_ws;

    k_pool<<<dim3(HO / 4, NB), 256, 0, stream>>>(x, pooled);
    k_rnn <<<dim3(NCHUNK), 64, 0, stream>>>(pooled, Wih, Whh, bih, bhh, Wfc, bfc, out);
}

// Round 5
// 128.003 us; speedup vs baseline: 2.5738x; 2.5738x over previous
//
#include <hip/hip_runtime.h>
#include <hip/hip_fp16.h>

#define CH   16
#define HID  32
#define HIN  254
#define WIN  254
#define HO   128
#define WO   128
#define NB   64
#define SLEN (HO * WO)          // 16384
#define CHUNK 32
#define WARM  16
#define NCHUNK (SLEN / CHUNK)   // 512

typedef _Float16 v8h __attribute__((ext_vector_type(8)));
typedef float    v4f __attribute__((ext_vector_type(4)));
typedef float    v2f __attribute__((ext_vector_type(2)));
typedef unsigned int v4u __attribute__((ext_vector_type(4)));
typedef unsigned int v2u __attribute__((ext_vector_type(2)));

__device__ __forceinline__ float fast_tanh(float x) {
    float ax = __builtin_fabsf(x);
    float e = exp2f(ax * -2.8853900817779268f);
    float r = (1.0f - e) * __builtin_amdgcn_rcpf(1.0f + e);
    return __builtin_copysignf(r, x);
}

// ---------------- K1: pad + L2 pool -> pooled f16 in (N, S, C) -----------
__global__ __launch_bounds__(256) void k_pool(const float* __restrict__ x,
                                              _Float16* __restrict__ pooled) {
    const int tid = threadIdx.x;
    const int px  = tid & 63;          // x-pair: outputs 2*px, 2*px+1
    const int wy  = tid >> 6;
    const int y   = blockIdx.x * 4 + wy;
    const int n   = blockIdx.y;

    int r[3];
#pragma unroll
    for (int k = 0; k < 3; ++k) r[k] = min(max(2 * y - 2 + k, 0), HIN - 1);

    const bool left  = (px == 0);
    const bool right = (px == 63);
    const int c0 = left  ? 0   : 4 * px - 2;
    const int c1 = 4 * px;
    const int c2 = right ? 252 : 4 * px + 2;

    const float* xn = x + (size_t)n * CH * HIN * WIN;
    _Float16 ph[2][CH];

#pragma unroll
    for (int cg = 0; cg < 4; ++cg) {
        v2f L[4][3][3];
#pragma unroll
        for (int cc = 0; cc < 4; ++cc) {
            const float* bc = xn + (size_t)(cg * 4 + cc) * HIN * WIN;
#pragma unroll
            for (int k = 0; k < 3; ++k) {
                const float* rp = bc + (size_t)r[k] * WIN;
                L[cc][k][0] = *(const v2f*)(rp + c0);
                L[cc][k][1] = *(const v2f*)(rp + c1);
                L[cc][k][2] = *(const v2f*)(rp + c2);
            }
        }
#pragma unroll
        for (int cc = 0; cc < 4; ++cc) {
            float s0 = 0.f, s1 = 0.f;
#pragma unroll
            for (int k = 0; k < 3; ++k) {
                v2f L0 = L[cc][k][0], L1 = L[cc][k][1], L2 = L[cc][k][2];
                if (left)  L0[1] = L0[0];
                if (right) L2[0] = L2[1];
                s0 += L0[0] * L0[0] + L0[1] * L0[1] + L1[0] * L1[0];
                s1 += L1[0] * L1[0] + L1[1] * L1[1] + L2[0] * L2[0];
            }
            ph[0][cg * 4 + cc] = (_Float16)sqrtf(s0);
            ph[1][cg * 4 + cc] = (_Float16)sqrtf(s1);
        }
    }

    const size_t t = (size_t)y * WO + 2 * px;
    v4u* dst = (v4u*)(pooled + ((size_t)n * SLEN + t) * CH);
    dst[0] = *(const v4u*)&ph[0][0];
    dst[1] = *(const v4u*)&ph[0][8];
    dst[2] = *(const v4u*)&ph[1][0];
    dst[3] = *(const v4u*)&ph[1][8];
}

// ---------------- K2: fused xproj + RNN + out-proj + residual ------------
// 4 waves/block, wave wid owns batches 16wid..16wid+15 (rows wave-private,
// zero barriers). MFMA 16x16x32_f16 mappings (g=l>>4, q=l&15):
//   A[m][k]: m=q, k=8g+e ; B[k][n]: n=q, k=8g+e ; D[m][n]: n=q, m=4g+r
// hbuf row b: [ h(32) | p(16) | zeros(16) | pad->72 ]  (144B rows)
// sbuf: f16 out-staging, [b][c*20 + tt] halfs, flushed every 16 t as 64B runs.
__global__ __launch_bounds__(256) void k_rnn(const _Float16* __restrict__ pooled,
                                             const float* __restrict__ Wih,
                                             const float* __restrict__ Whh,
                                             const float* __restrict__ bih,
                                             const float* __restrict__ bhh,
                                             const float* __restrict__ Wfc,
                                             const float* __restrict__ bfc,
                                             float* __restrict__ out) {
    const int tid = threadIdx.x;
    const int wid = tid >> 6;
    const int l   = tid & 63;
    const int g   = l >> 4;
    const int q   = l & 15;
    const int rowq = wid * 16 + q;
    const int cid = blockIdx.x;
    const int start = cid * CHUNK;
    const int warm  = min(WARM, start);   // 16, or 0 for cid==0
    const int t0    = start - warm;

    __shared__ _Float16 hbuf[64][72];     // 9216 B
    __shared__ _Float16 sbuf[64][324];    // 41472 B

    {   // zero the K-pad region (cols 48..63) of this wave's rows
        v4u z = {0u, 0u, 0u, 0u};
        *(v4u*)&hbuf[rowq][48 + 8 * (g & 1)] = z;
    }

    // constant B fragments
    v8h bWhh[2], bWih[2], bWfc;
#pragma unroll
    for (int nt = 0; nt < 2; ++nt) {
        const float* wr = Whh + (size_t)(nt * 16 + q) * HID + 8 * g;
#pragma unroll
        for (int e = 0; e < 8; ++e) bWhh[nt][e] = (_Float16)wr[e];
        const float* wi = Wih + (size_t)(nt * 16 + q) * CH;
#pragma unroll
        for (int e = 0; e < 8; ++e)
            bWih[nt][e] = (g < 2) ? (_Float16)wi[8 * g + e] : (_Float16)0.f;
    }
#pragma unroll
    for (int e = 0; e < 8; ++e) bWfc[e] = (_Float16)Wfc[(size_t)q * HID + 8 * g + e];

    float biasH[2];
#pragma unroll
    for (int nt = 0; nt < 2; ++nt) biasH[nt] = bih[nt * 16 + q] + bhh[nt * 16 + q];
    const float biasC = bfc[q];

    v8h af;                               // h-state A-fragment (1 m-tile/wave)
#pragma unroll
    for (int e = 0; e < 8; ++e) af[e] = (_Float16)0.f;

    // lane (g,q) streams batch rowq, channel-quarter 4g..4g+3 (8B/step)
    const _Float16* pb = pooled + (size_t)rowq * SLEN * CH + 4 * g;
    v2u pA = *(const v2u*)(pb + (size_t)t0 * CH);
    v2u pB = *(const v2u*)(pb + (size_t)(t0 + 1) * CH);

#define RNN_STEP(PRE, TT, EMIT, TTL)                                           \
    {                                                                          \
        const int t = (TT);                                                    \
        *(v2u*)&hbuf[rowq][32 + 4 * g] = PRE;                                  \
        {                                                                      \
            int tn = t + 2; if (tn > SLEN - 1) tn = SLEN - 1;                  \
            PRE = *(const v2u*)(pb + (size_t)tn * CH);                         \
        }                                                                      \
        v8h pf = *(const v8h*)&hbuf[rowq][32 + 8 * g];                         \
        v4f acc0, acc1;                                                        \
        {                                                                      \
            v4f ai = {biasH[0], biasH[0], biasH[0], biasH[0]};                 \
            ai = __builtin_amdgcn_mfma_f32_16x16x32_f16(pf, bWih[0], ai, 0, 0, 0); \
            acc0 = __builtin_amdgcn_mfma_f32_16x16x32_f16(af, bWhh[0], ai, 0, 0, 0); \
        }                                                                      \
        {                                                                      \
            v4f ai = {biasH[1], biasH[1], biasH[1], biasH[1]};                 \
            ai = __builtin_amdgcn_mfma_f32_16x16x32_f16(pf, bWih[1], ai, 0, 0, 0); \
            acc1 = __builtin_amdgcn_mfma_f32_16x16x32_f16(af, bWhh[1], ai, 0, 0, 0); \
        }                                                                      \
        _Pragma("unroll")                                                      \
        for (int r = 0; r < 4; ++r) {                                          \
            hbuf[wid * 16 + 4 * g + r][q]      = (_Float16)fast_tanh(acc0[r]); \
            hbuf[wid * 16 + 4 * g + r][16 + q] = (_Float16)fast_tanh(acc1[r]); \
        }                                                                      \
        af = *(const v8h*)&hbuf[rowq][8 * g];                                  \
        if (EMIT) {                                                            \
            v4f pj = {biasC, biasC, biasC, biasC};                             \
            pj = __builtin_amdgcn_mfma_f32_16x16x32_f16(af, bWfc, pj, 0, 0, 0);\
            _Pragma("unroll")                                                  \
            for (int r = 0; r < 4; ++r) {                                      \
                const int b = wid * 16 + 4 * g + r;                            \
                float res = (float)hbuf[b][32 + q];                            \
                sbuf[b][q * 20 + (TTL)] = (_Float16)(pj[r] + res);             \
            }                                                                  \
        }                                                                      \
    }

#define FLUSH(TBASE)                                                           \
    {                                                                          \
        _Pragma("unroll")                                                      \
        for (int i = 0; i < 4; ++i) {                                          \
            const int pl = l + 64 * i;                                         \
            const int b  = wid * 16 + (pl >> 4);                               \
            const int c  = pl & 15;                                            \
            const __half2* sp = (const __half2*)&sbuf[b][c * 20];              \
            float* op = out + (size_t)(b * CH + c) * SLEN + (TBASE);           \
            _Pragma("unroll")                                                  \
            for (int j = 0; j < 4; ++j) {                                      \
                float2 f0 = __half22float2(sp[2 * j]);                         \
                float2 f1 = __half22float2(sp[2 * j + 1]);                     \
                v4f v = {f0.x, f0.y, f1.x, f1.y};                              \
                *(v4f*)(op + 4 * j) = v;                                       \
            }                                                                  \
        }                                                                      \
    }

    if (warm) {
#pragma unroll 2
        for (int st = 0; st < WARM; st += 2) {
            RNN_STEP(pA, t0 + st,     0, 0)
            RNN_STEP(pB, t0 + st + 1, 0, 0)
        }
    }
#pragma unroll 2
    for (int st = 0; st < 16; st += 2) {
        RNN_STEP(pA, start + st,     1, st)
        RNN_STEP(pB, start + st + 1, 1, st + 1)
    }
    FLUSH(start)
#pragma unroll 2
    for (int st = 0; st < 16; st += 2) {
        RNN_STEP(pA, start + 16 + st,     1, st)
        RNN_STEP(pB, start + 16 + st + 1, 1, st + 1)
    }
    FLUSH(start + 16)
#undef RNN_STEP
#undef FLUSH
}

__global__ void k_sentinel(float* o) { o[threadIdx.x] = -12345.0f; }

extern "C" void kernel_launch(void* const* d_in, const int* in_sizes, int n_in,
                              void* d_out, int out_size, void* d_ws, size_t ws_size,
                              hipStream_t stream) {
    const float* x   = (const float*)d_in[0];
    const float* Wih = (const float*)d_in[1];
    const float* Whh = (const float*)d_in[2];
    const float* bih = (const float*)d_in[3];
    const float* bhh = (const float*)d_in[4];
    const float* Wfc = (const float*)d_in[5];
    const float* bfc = (const float*)d_in[6];
    float* out = (float*)d_out;

    const size_t poolB = (size_t)NB * SLEN * CH * sizeof(_Float16);  // 32 MiB
    if (ws_size < poolB) {
        k_sentinel<<<1, 64, 0, stream>>>(out);
        return;
    }
    _Float16* pooled = (_Float16*)d_ws;

    k_pool<<<dim3(HO / 4, NB), 256, 0, stream>>>(x, pooled);
    k_rnn <<<dim3(NCHUNK), 256, 0, stream>>>(pooled, Wih, Whh, bih, bhh, Wfc, bfc, out);
}